// Round 2
// baseline (1720.759 us; speedup 1.0000x reference)
//
#include <hip/hip_runtime.h>
#include <hip/hip_bf16.h>
#include <math.h>

typedef __attribute__((ext_vector_type(4))) float fvec4;
typedef __attribute__((ext_vector_type(2))) float fvec2;
typedef __attribute__((ext_vector_type(4))) int ivec4;
typedef __attribute__((ext_vector_type(4))) unsigned short usvec4;
typedef __attribute__((ext_vector_type(8))) short bf16x8;

#define SEQ 2048
#define DMODEL 2048
#define DINNER 4096
#define DSTATE 16
#define DTRANK 128
#define NB 4
#define MROWS (NB*SEQ)  // 8192

__device__ __forceinline__ float bf2f(unsigned short h){
  union{unsigned int u; float f;} v; v.u = ((unsigned int)h)<<16; return v.f;
}
__device__ __forceinline__ unsigned short f2bf(float f){
  union{float f; unsigned int u;} v; v.f=f;
  unsigned int r = v.u + 0x7fffu + ((v.u>>16)&1u);
  return (unsigned short)(r>>16);
}
__device__ __forceinline__ void async16(const void* g, void* l){
  __builtin_amdgcn_global_load_lds((const __attribute__((address_space(1))) void*)g,
                                   (__attribute__((address_space(3))) void*)l, 16, 0, 0);
}
__device__ __forceinline__ float sigf(float x){ return 1.f/(1.f+__expf(-x)); }

// ---------------- fp32 -> bf16 convert ----------------
__global__ void cvt_bf16_kernel(const float* __restrict__ in, unsigned short* __restrict__ out, int n){
  int i = (blockIdx.x*256 + threadIdx.x)*4;
  if (i >= n) return;
  fvec4 v = *(const fvec4*)(in + i);
  usvec4 o;
  o[0]=f2bf(v[0]); o[1]=f2bf(v[1]); o[2]=f2bf(v[2]); o[3]=f2bf(v[3]);
  *(usvec4*)(out + i) = o;
}

// ---------------- GEMM: C[M,N] = A[M,K] * B[N,K]^T, bf16 MFMA ----------------
// MODE 0: split x/z bf16 (N=8192 -> Cb1 cols<4096, Cb2 rest)
// MODE 1: fp32 store, guard col<Nreal (x_proj)
// MODE 2: softplus(v+bias) -> bf16 (dt_proj -> delta)
// MODE 3: fp32 store to d_out (out_proj)
template<int MODE>
__global__ __launch_bounds__(256) void gemm_bt(
    const unsigned short* __restrict__ A,
    const unsigned short* __restrict__ B,
    int K, int Nreal,
    float* __restrict__ Cf,
    unsigned short* __restrict__ Cb1,
    unsigned short* __restrict__ Cb2,
    const float* __restrict__ bias,
    int ldc)
{
  __shared__ __align__(16) unsigned short As[128*32];
  __shared__ __align__(16) unsigned short Bs[128*32];
  const int t = threadIdx.x;
  const int bx = blockIdx.x, by = blockIdx.y;
  const int wave = t>>6, lane = t&63;
  const int wr = (wave>>1)*64, wc = (wave&1)*64;
  const int fr = lane&15, fc = lane>>4;
  fvec4 acc[4][4];
  #pragma unroll
  for(int i=0;i<4;i++){
    #pragma unroll
    for(int j=0;j<4;j++){ acc[i][j] = (fvec4)(0.f); }
  }
  const int srow = t>>2;
  const int scol = (t&3)*8;
  long rowA = (long)by*128 + srow;
  int rB0 = bx*128 + srow;      if (rB0 > Nreal-1) rB0 = Nreal-1;
  int rB1 = bx*128 + 64 + srow; if (rB1 > Nreal-1) rB1 = Nreal-1;
  const unsigned short* gA0 = A + rowA*(long)K + scol;
  const unsigned short* gA1 = gA0 + 64L*K;
  const unsigned short* gB0 = B + (long)rB0*K + scol;
  const unsigned short* gB1 = B + (long)rB1*K + scol;
  unsigned short* lA0 = &As[t*8];
  unsigned short* lA1 = &As[2048 + t*8];
  unsigned short* lB0 = &Bs[t*8];
  unsigned short* lB1 = &Bs[2048 + t*8];

  for (int k0 = 0; k0 < K; k0 += 32){
    async16(gA0 + k0, lA0);
    async16(gA1 + k0, lA1);
    async16(gB0 + k0, lB0);
    async16(gB1 + k0, lB1);
    __syncthreads();   // drains vmcnt -> LDS tiles valid
    bf16x8 af[4], bv[4];
    #pragma unroll
    for(int i=0;i<4;i++){
      af[i] = *(const bf16x8*)&As[(wr + i*16 + fr)*32 + fc*8];
      bv[i] = *(const bf16x8*)&Bs[(wc + i*16 + fr)*32 + fc*8];
    }
    #pragma unroll
    for(int i=0;i<4;i++){
      #pragma unroll
      for(int j=0;j<4;j++){
        acc[i][j] = __builtin_amdgcn_mfma_f32_16x16x32_bf16(af[i], bv[j], acc[i][j], 0,0,0);
      }
    }
    __syncthreads();   // protect LDS from next iter's staging
  }

  const long crow0 = (long)by*128 + wr;
  const int ccol0 = bx*128 + wc;
  #pragma unroll
  for(int i=0;i<4;i++){
    #pragma unroll
    for(int j=0;j<4;j++){
      #pragma unroll
      for(int q=0;q<4;q++){
        long rg = crow0 + i*16 + fc*4 + q;
        int  cg = ccol0 + j*16 + fr;
        float v = acc[i][j][q];
        if (MODE==0){
          if (cg < DINNER) Cb1[rg*DINNER + cg] = f2bf(v);
          else             Cb2[rg*DINNER + (cg-DINNER)] = f2bf(v);
        } else if (MODE==1){
          if (cg < Nreal) Cf[rg*ldc + cg] = v;
        } else if (MODE==2){
          float x = v + bias[cg];
          float sp = (x > 20.f) ? x : log1pf(__expf(x));
          Cb1[rg*ldc + cg] = f2bf(sp);
        } else {
          Cf[rg*ldc + cg] = v;
        }
      }
    }
  }
}

// ---------------- depthwise causal conv(4) + bias + SiLU ----------------
__global__ __launch_bounds__(256) void conv_silu_kernel(
    const unsigned short* __restrict__ xb, const float* __restrict__ w,
    const float* __restrict__ bias, unsigned short* __restrict__ ub)
{
  int gid = blockIdx.x*256 + threadIdx.x;
  int d0 = (gid & 511)*8;           // 4096/8 = 512 threads per row
  long m = gid >> 9;                // b*SEQ + l
  int l = (int)(m & (SEQ-1));
  fvec4 w4[8];
  #pragma unroll
  for(int k=0;k<8;k++) w4[k] = *(const fvec4*)&w[(d0+k)*4];
  float acc[8];
  fvec4 b0 = *(const fvec4*)&bias[d0];
  fvec4 b1 = *(const fvec4*)&bias[d0+4];
  acc[0]=b0[0];acc[1]=b0[1];acc[2]=b0[2];acc[3]=b0[3];
  acc[4]=b1[0];acc[5]=b1[1];acc[6]=b1[2];acc[7]=b1[3];
  #pragma unroll
  for(int j=0;j<4;j++){
    int lj = l-3+j;
    if (lj >= 0){
      ivec4 xv = *(const ivec4*)&xb[(m-3+j)*DINNER + d0];
      float xs[8];
      #pragma unroll
      for(int q=0;q<4;q++){
        unsigned int wd = (unsigned int)xv[q];
        xs[2*q]   = bf2f((unsigned short)(wd & 0xffffu));
        xs[2*q+1] = bf2f((unsigned short)(wd >> 16));
      }
      #pragma unroll
      for(int k=0;k<8;k++) acc[k] += xs[k]*w4[k][j];
    }
  }
  ivec4 ov;
  #pragma unroll
  for(int q=0;q<4;q++){
    float y0 = acc[2*q]  * sigf(acc[2*q]);
    float y1 = acc[2*q+1]* sigf(acc[2*q+1]);
    ov[q] = (int)((unsigned)f2bf(y0) | ((unsigned)f2bf(y1) << 16));
  }
  *(ivec4*)&ub[m*DINNER + d0] = ov;
}

// ---------------- new_conv_state = x[:, L-4:, :] transposed ----------------
__global__ void conv_state_kernel(const unsigned short* __restrict__ xb, float* __restrict__ out){
  int i = blockIdx.x*256 + threadIdx.x;     // 65536 total: b*16384 + d*4 + j
  int b = i >> 14; int r = i & 16383; int dd = r >> 2; int j = r & 3;
  out[i] = bf2f(xb[((long)(b*SEQ + (SEQ-4) + j))*DINNER + dd]);
}

// ---------------- xdbl[:, :128] -> bf16 for dt_proj A ----------------
__global__ void cvt_dtr_kernel(const float* __restrict__ xdbl, unsigned short* __restrict__ dtr){
  int i = blockIdx.x*256 + threadIdx.x;     // per 4 elems, 8192*32 total
  long mrow = i >> 5; int c = (i & 31)*4;
  fvec4 v = *(const fvec4*)&xdbl[mrow*160 + c];
  usvec4 o; o[0]=f2bf(v[0]); o[1]=f2bf(v[1]); o[2]=f2bf(v[2]); o[3]=f2bf(v[3]);
  *(usvec4*)&dtr[mrow*DTRANK + c] = o;
}

// ---------------- selective scan ----------------
// 8 threads per (b,d) channel; 2 states per thread. grid=512 blocks x 256 thr.
// NOTE: y_b may alias u_b (in-place). Safe: each (m,d) is touched only by its
// owning 8 lanes (same wave); u[m]/z[m]/delta[m] loads are consumed (waitcnt)
// before the y[m] store is issued, and prefetch reads run >=2 rows ahead of
// the write cursor, never revisiting a written row.
__global__ __launch_bounds__(256) void scan_kernel(
    const unsigned short* __restrict__ delta_b,
    const unsigned short* __restrict__ u_b,
    const unsigned short* __restrict__ z_b,
    const float* __restrict__ xdbl,     // (8192,160): B at 128, C at 144
    const float* __restrict__ Amat,     // (16,4096)
    const float* __restrict__ Dvec,     // (4096)
    unsigned short* __restrict__ y_b,   // (8192,4096)
    float* __restrict__ last_state)     // (4,16,4096)
{
  const int t = threadIdx.x;
  const int sub = t & 7, ch = t >> 3;
  const int blk = blockIdx.x;
  const int b = blk >> 7;
  const int d = (blk & 127)*32 + ch;
  const float a0 = Amat[(sub*2+0)*DINNER + d];
  const float a1 = Amat[(sub*2+1)*DINNER + d];
  const float Dd = Dvec[d];
  float s0 = 0.f, s1 = 0.f;
  const long m0 = (long)b*SEQ;

  float dA_,uA_,zA_, dB_,uB_,zB_;
  fvec2 BA_,CA_, BB_,CB_;

#define SLOAD(L_, sd,su,sz,sB,sC) { \
    long _idx = (m0+(L_))*(long)DINNER + d; \
    long _mb  = (m0+(L_))*160L; \
    sd = bf2f(delta_b[_idx]); su = bf2f(u_b[_idx]); sz = bf2f(z_b[_idx]); \
    sB = *(const fvec2*)&xdbl[_mb + 128 + sub*2]; \
    sC = *(const fvec2*)&xdbl[_mb + 144 + sub*2]; }

#define SCOMP(sd,su,sz,sB,sC, L_) { \
    float dBu = sd*su; \
    float e0 = __expf(sd*a0); float e1 = __expf(sd*a1); \
    s0 = e0*s0 + sB[0]*dBu; s1 = e1*s1 + sB[1]*dBu; \
    float yp = s0*sC[0] + s1*sC[1]; \
    yp += __shfl_xor(yp,1); yp += __shfl_xor(yp,2); yp += __shfl_xor(yp,4); \
    if (sub == 0){ \
      float yy = yp + su*Dd; \
      float zs = sz*sigf(sz); \
      y_b[(m0+(L_))*(long)DINNER + d] = f2bf(yy*zs); } }

  SLOAD(0, dA_,uA_,zA_,BA_,CA_);
  SLOAD(1, dB_,uB_,zB_,BB_,CB_);
  for (int l = 0; l < SEQ; l += 2){
    SCOMP(dA_,uA_,zA_,BA_,CA_, l);
    { int lp = l+2; if (lp > SEQ-1) lp = SEQ-1; SLOAD(lp, dA_,uA_,zA_,BA_,CA_); }
    SCOMP(dB_,uB_,zB_,BB_,CB_, l+1);
    { int lp = l+3; if (lp > SEQ-1) lp = SEQ-1; SLOAD(lp, dB_,uB_,zB_,BB_,CB_); }
  }
#undef SLOAD
#undef SCOMP
  long off = (long)b*(DSTATE*DINNER) + (long)(sub*2)*DINNER + d;
  last_state[off] = s0;
  last_state[off + DINNER] = s1;
}

// ---------------- launcher ----------------
// Workspace budget: fits in EXACTLY 256 MiB via lifetime aliasing:
//   Slot A [0,64M):    hs_b(32M)+w_in_b(32M)  -> delta(64M) after in_proj
//   Slot B [64,128M):  x(64M) -> after conv: wxp(1.25)/wdt(1)/wout(16)/xdbl(5)/dtr(2)
//   Slot C [128,192M): z(64M)
//   Slot D [192,256M): u(64M) -> y written in-place by scan
// If ws_size is generous (>=362MiB) use a plain non-aliased layout instead.
extern "C" void kernel_launch(void* const* d_in, const int* in_sizes, int n_in,
                              void* d_out, int out_size, void* d_ws, size_t ws_size,
                              hipStream_t stream) {
  const float* hs     = (const float*)d_in[0];
  const float* w_in   = (const float*)d_in[6];
  const float* conv_w = (const float*)d_in[7];
  const float* conv_b = (const float*)d_in[8];
  const float* w_xp   = (const float*)d_in[9];
  const float* w_dt   = (const float*)d_in[10];
  const float* dt_bias= (const float*)d_in[11];
  const float* Amat   = (const float*)d_in[12];
  const float* Dvec   = (const float*)d_in[13];
  const float* w_out  = (const float*)d_in[14];
  float* out = (float*)d_out;

  char* ws = (char*)d_ws;
  const size_t MiB = (size_t)1 << 20;

  unsigned short *hs_b, *w_in_b, *x_b, *z_b, *u_b, *delta_b;
  unsigned short *wxp_b, *wdt_b, *wout_b, *dtr_b, *y_b;
  float *xdbl;

  if (ws_size >= 362*MiB){
    // plain layout
    size_t off = 0;
    auto alloc = [&](size_t bytes)->void*{ void* p = ws + off; off += (bytes + 255) & ~(size_t)255; return p; };
    hs_b   = (unsigned short*)alloc((size_t)MROWS*DMODEL*2);
    w_in_b = (unsigned short*)alloc((size_t)2*DINNER*DMODEL*2);
    x_b    = (unsigned short*)alloc((size_t)MROWS*DINNER*2);
    z_b    = (unsigned short*)alloc((size_t)MROWS*DINNER*2);
    u_b    = (unsigned short*)alloc((size_t)MROWS*DINNER*2);
    delta_b= (unsigned short*)alloc((size_t)MROWS*DINNER*2);
    wxp_b  = (unsigned short*)alloc((size_t)160*DINNER*2);
    wdt_b  = (unsigned short*)alloc((size_t)DINNER*DTRANK*2);
    wout_b = (unsigned short*)alloc((size_t)DMODEL*DINNER*2);
    xdbl   = (float*)alloc((size_t)MROWS*160*4);
    dtr_b  = (unsigned short*)alloc((size_t)MROWS*DTRANK*2);
    y_b    = x_b;   // x dead after conv/conv_state
  } else {
    // aliased 256 MiB layout
    hs_b    = (unsigned short*)(ws + 0);
    w_in_b  = (unsigned short*)(ws + 32*MiB);
    delta_b = (unsigned short*)(ws + 0);        // over hs_b+w_in_b (dead after in_proj)
    x_b     = (unsigned short*)(ws + 64*MiB);
    wxp_b   = (unsigned short*)(ws + 64*MiB);   // over x (dead after conv)
    wdt_b   = (unsigned short*)(ws + 66*MiB);
    wout_b  = (unsigned short*)(ws + 68*MiB);
    xdbl    = (float*)         (ws + 84*MiB);
    dtr_b   = (unsigned short*)(ws + 90*MiB);
    z_b     = (unsigned short*)(ws + 128*MiB);
    u_b     = (unsigned short*)(ws + 192*MiB);
    y_b     = u_b;                              // in-place (see scan_kernel note)
  }

  // 1) converts needed for in_proj
  cvt_bf16_kernel<<<(MROWS*DMODEL)/1024, 256, 0, stream>>>(hs, hs_b, MROWS*DMODEL);
  cvt_bf16_kernel<<<(2*DINNER*DMODEL)/1024, 256, 0, stream>>>(w_in, w_in_b, 2*DINNER*DMODEL);

  // 2) in_proj: (8192x2048) @ (8192x2048)^T -> split x/z bf16
  gemm_bt<0><<<dim3(64,64), 256, 0, stream>>>(hs_b, w_in_b, DMODEL, 2*DINNER,
                                              nullptr, x_b, z_b, nullptr, 0);
  // 3) new_conv_state output (reads x)
  conv_state_kernel<<<256, 256, 0, stream>>>(x_b, out + (size_t)MROWS*DMODEL);
  // 4) conv + silu -> u (reads x; x dead afterwards)
  conv_silu_kernel<<<(MROWS*512)/256, 256, 0, stream>>>(x_b, conv_w, conv_b, u_b);

  // 5) weight converts (into dead-x slot in aliased mode)
  cvt_bf16_kernel<<<(160*DINNER)/1024, 256, 0, stream>>>(w_xp, wxp_b, 160*DINNER);
  cvt_bf16_kernel<<<(DINNER*DTRANK)/1024, 256, 0, stream>>>(w_dt, wdt_b, DINNER*DTRANK);
  cvt_bf16_kernel<<<(DMODEL*DINNER)/1024, 256, 0, stream>>>(w_out, wout_b, DMODEL*DINNER);

  // 6) x_proj: (8192x4096) @ (160x4096)^T -> xdbl fp32 (ldc=160)
  gemm_bt<1><<<dim3(2,64), 256, 0, stream>>>(u_b, wxp_b, DINNER, 160,
                                             xdbl, nullptr, nullptr, nullptr, 160);
  // 7) dtr bf16
  cvt_dtr_kernel<<<(MROWS*32)/256, 256, 0, stream>>>(xdbl, dtr_b);
  // 8) dt_proj + softplus -> delta bf16 (into slot A, dead hs/w_in)
  gemm_bt<2><<<dim3(32,64), 256, 0, stream>>>(dtr_b, wdt_b, DTRANK, DINNER,
                                              nullptr, delta_b, nullptr, dt_bias, DINNER);
  // 9) scan -> y (in-place over u in aliased mode) + last_state
  scan_kernel<<<512, 256, 0, stream>>>(delta_b, u_b, z_b, xdbl, Amat, Dvec,
                                       y_b, out + (size_t)MROWS*DMODEL + NB*DINNER*4);
  // 10) out_proj: (8192x4096) @ (2048x4096)^T -> out fp32
  gemm_bt<3><<<dim3(16,64), 256, 0, stream>>>(y_b, wout_b, DINNER, DMODEL,
                                              out, nullptr, nullptr, nullptr, DMODEL);
}

// Round 3
// 1163.673 us; speedup vs baseline: 1.4787x; 1.4787x over previous
//
#include <hip/hip_runtime.h>
#include <hip/hip_bf16.h>
#include <math.h>

typedef __attribute__((ext_vector_type(4))) float fvec4;
typedef __attribute__((ext_vector_type(2))) float fvec2;
typedef __attribute__((ext_vector_type(4))) int ivec4;
typedef __attribute__((ext_vector_type(4))) unsigned short usvec4;
typedef __attribute__((ext_vector_type(8))) short bf16x8;

#define SEQ 2048
#define DMODEL 2048
#define DINNER 4096
#define DSTATE 16
#define DTRANK 128
#define NB 4
#define MROWS (NB*SEQ)  // 8192
#define NCHUNK 16
#define LC (SEQ/NCHUNK) // 128

__device__ __forceinline__ float bf2f(unsigned short h){
  union{unsigned int u; float f;} v; v.u = ((unsigned int)h)<<16; return v.f;
}
__device__ __forceinline__ unsigned short f2bf(float f){
  union{float f; unsigned int u;} v; v.f=f;
  unsigned int r = v.u + 0x7fffu + ((v.u>>16)&1u);
  return (unsigned short)(r>>16);
}
__device__ __forceinline__ void async16(const void* g, void* l){
  __builtin_amdgcn_global_load_lds((const __attribute__((address_space(1))) void*)g,
                                   (__attribute__((address_space(3))) void*)l, 16, 0, 0);
}
__device__ __forceinline__ float sigf(float x){ return 1.f/(1.f+__expf(-x)); }

// ---------------- fp32 -> bf16 convert ----------------
__global__ void cvt_bf16_kernel(const float* __restrict__ in, unsigned short* __restrict__ out, int n){
  int i = (blockIdx.x*256 + threadIdx.x)*4;
  if (i >= n) return;
  fvec4 v = *(const fvec4*)(in + i);
  usvec4 o;
  o[0]=f2bf(v[0]); o[1]=f2bf(v[1]); o[2]=f2bf(v[2]); o[3]=f2bf(v[3]);
  *(usvec4*)(out + i) = o;
}

// ---------------- GEMM: C[M,N] = A[M,K] * B[N,K]^T, bf16 MFMA ----------------
// MODE 0: split x/z bf16 (N=8192 -> Cb1 cols<4096, Cb2 rest)
// MODE 1: fp32 store, guard col<Nreal (x_proj)
// MODE 2: softplus(v+bias) -> bf16 (dt_proj -> delta)
// MODE 3: fp32 store to d_out (out_proj)
template<int MODE>
__global__ __launch_bounds__(256) void gemm_bt(
    const unsigned short* __restrict__ A,
    const unsigned short* __restrict__ B,
    int K, int Nreal,
    float* __restrict__ Cf,
    unsigned short* __restrict__ Cb1,
    unsigned short* __restrict__ Cb2,
    const float* __restrict__ bias,
    int ldc)
{
  __shared__ __align__(16) unsigned short As[128*32];
  __shared__ __align__(16) unsigned short Bs[128*32];
  const int t = threadIdx.x;
  const int bx = blockIdx.x, by = blockIdx.y;
  const int wave = t>>6, lane = t&63;
  const int wr = (wave>>1)*64, wc = (wave&1)*64;
  const int fr = lane&15, fc = lane>>4;
  fvec4 acc[4][4];
  #pragma unroll
  for(int i=0;i<4;i++){
    #pragma unroll
    for(int j=0;j<4;j++){ acc[i][j] = (fvec4)(0.f); }
  }
  const int srow = t>>2;
  const int scol = (t&3)*8;
  long rowA = (long)by*128 + srow;
  int rB0 = bx*128 + srow;      if (rB0 > Nreal-1) rB0 = Nreal-1;
  int rB1 = bx*128 + 64 + srow; if (rB1 > Nreal-1) rB1 = Nreal-1;
  const unsigned short* gA0 = A + rowA*(long)K + scol;
  const unsigned short* gA1 = gA0 + 64L*K;
  const unsigned short* gB0 = B + (long)rB0*K + scol;
  const unsigned short* gB1 = B + (long)rB1*K + scol;
  unsigned short* lA0 = &As[t*8];
  unsigned short* lA1 = &As[2048 + t*8];
  unsigned short* lB0 = &Bs[t*8];
  unsigned short* lB1 = &Bs[2048 + t*8];

  for (int k0 = 0; k0 < K; k0 += 32){
    async16(gA0 + k0, lA0);
    async16(gA1 + k0, lA1);
    async16(gB0 + k0, lB0);
    async16(gB1 + k0, lB1);
    __syncthreads();   // drains vmcnt -> LDS tiles valid
    bf16x8 af[4], bv[4];
    #pragma unroll
    for(int i=0;i<4;i++){
      af[i] = *(const bf16x8*)&As[(wr + i*16 + fr)*32 + fc*8];
      bv[i] = *(const bf16x8*)&Bs[(wc + i*16 + fr)*32 + fc*8];
    }
    #pragma unroll
    for(int i=0;i<4;i++){
      #pragma unroll
      for(int j=0;j<4;j++){
        acc[i][j] = __builtin_amdgcn_mfma_f32_16x16x32_bf16(af[i], bv[j], acc[i][j], 0,0,0);
      }
    }
    __syncthreads();   // protect LDS from next iter's staging
  }

  const long crow0 = (long)by*128 + wr;
  const int ccol0 = bx*128 + wc;
  #pragma unroll
  for(int i=0;i<4;i++){
    #pragma unroll
    for(int j=0;j<4;j++){
      #pragma unroll
      for(int q=0;q<4;q++){
        long rg = crow0 + i*16 + fc*4 + q;
        int  cg = ccol0 + j*16 + fr;
        float v = acc[i][j][q];
        if (MODE==0){
          if (cg < DINNER) Cb1[rg*DINNER + cg] = f2bf(v);
          else             Cb2[rg*DINNER + (cg-DINNER)] = f2bf(v);
        } else if (MODE==1){
          if (cg < Nreal) Cf[rg*ldc + cg] = v;
        } else if (MODE==2){
          float x = v + bias[cg];
          float sp = (x > 20.f) ? x : log1pf(__expf(x));
          Cb1[rg*ldc + cg] = f2bf(sp);
        } else {
          Cf[rg*ldc + cg] = v;
        }
      }
    }
  }
}

// ---------------- depthwise causal conv(4) + bias + SiLU ----------------
__global__ __launch_bounds__(256) void conv_silu_kernel(
    const unsigned short* __restrict__ xb, const float* __restrict__ w,
    const float* __restrict__ bias, unsigned short* __restrict__ ub)
{
  int gid = blockIdx.x*256 + threadIdx.x;
  int d0 = (gid & 511)*8;           // 4096/8 = 512 threads per row
  long m = gid >> 9;                // b*SEQ + l
  int l = (int)(m & (SEQ-1));
  fvec4 w4[8];
  #pragma unroll
  for(int k=0;k<8;k++) w4[k] = *(const fvec4*)&w[(d0+k)*4];
  float acc[8];
  fvec4 b0 = *(const fvec4*)&bias[d0];
  fvec4 b1 = *(const fvec4*)&bias[d0+4];
  acc[0]=b0[0];acc[1]=b0[1];acc[2]=b0[2];acc[3]=b0[3];
  acc[4]=b1[0];acc[5]=b1[1];acc[6]=b1[2];acc[7]=b1[3];
  #pragma unroll
  for(int j=0;j<4;j++){
    int lj = l-3+j;
    if (lj >= 0){
      ivec4 xv = *(const ivec4*)&xb[(m-3+j)*DINNER + d0];
      float xs[8];
      #pragma unroll
      for(int q=0;q<4;q++){
        unsigned int wd = (unsigned int)xv[q];
        xs[2*q]   = bf2f((unsigned short)(wd & 0xffffu));
        xs[2*q+1] = bf2f((unsigned short)(wd >> 16));
      }
      #pragma unroll
      for(int k=0;k<8;k++) acc[k] += xs[k]*w4[k][j];
    }
  }
  ivec4 ov;
  #pragma unroll
  for(int q=0;q<4;q++){
    float y0 = acc[2*q]  * sigf(acc[2*q]);
    float y1 = acc[2*q+1]* sigf(acc[2*q+1]);
    ov[q] = (int)((unsigned)f2bf(y0) | ((unsigned)f2bf(y1) << 16));
  }
  *(ivec4*)&ub[m*DINNER + d0] = ov;
}

// ---------------- new_conv_state = x[:, L-4:, :] transposed ----------------
__global__ void conv_state_kernel(const unsigned short* __restrict__ xb, float* __restrict__ out){
  int i = blockIdx.x*256 + threadIdx.x;     // 65536 total: b*16384 + d*4 + j
  int b = i >> 14; int r = i & 16383; int dd = r >> 2; int j = r & 3;
  out[i] = bf2f(xb[((long)(b*SEQ + (SEQ-4) + j))*DINNER + dd]);
}

// ---------------- xdbl[:, :128] -> bf16 for dt_proj A ----------------
__global__ void cvt_dtr_kernel(const float* __restrict__ xdbl, unsigned short* __restrict__ dtr){
  int i = blockIdx.x*256 + threadIdx.x;     // per 4 elems, 8192*32 total
  long mrow = i >> 5; int c = (i & 31)*4;
  fvec4 v = *(const fvec4*)&xdbl[mrow*160 + c];
  usvec4 o; o[0]=f2bf(v[0]); o[1]=f2bf(v[1]); o[2]=f2bf(v[2]); o[3]=f2bf(v[3]);
  *(usvec4*)&dtr[mrow*DTRANK + c] = o;
}

// ================= chunked parallel scan =================
// Thread = one (b, d, chunk) channel, all 16 states in registers.
// Lanes = 64 consecutive d -> delta/u/z loads are 128B/wave coalesced;
// B/C rows are wave-uniform broadcasts. 1024 blocks -> ~16 waves/CU.

// K1: local scan from 0 -> S[(b,c,n,d)] (fp32), sum-of-delta -> sdelta[(b,c,d)]
__global__ __launch_bounds__(256) void scan_part1(
    const unsigned short* __restrict__ delta_b,
    const unsigned short* __restrict__ u_b,
    const float* __restrict__ xdbl,
    const float* __restrict__ Amat,
    float* __restrict__ S,
    float* __restrict__ sdelta)
{
  const int t = threadIdx.x;
  const int blk = blockIdx.x;
  const int c = blk & 15, b = (blk>>4)&3, d = (blk>>6)*256 + t;
  float a[16], s[16];
  #pragma unroll
  for (int n=0;n<16;n++){ a[n] = Amat[n*DINNER+d]; s[n]=0.f; }
  float sd = 0.f;
  const long mbase = (long)b*SEQ + c*LC;
  for (int l=0;l<LC;l++){
    long m = mbase + l;
    float dl = bf2f(delta_b[m*DINNER+d]);
    float ul = bf2f(u_b[m*DINNER+d]);
    const float* xb = &xdbl[m*160 + 128];
    float dbu = dl*ul;
    sd += dl;
    #pragma unroll
    for (int g=0; g<4; g++){
      fvec4 Bg = *(const fvec4*)(xb + 4*g);
      #pragma unroll
      for (int q=0;q<4;q++){
        int n = g*4+q;
        s[n] = __expf(dl*a[n])*s[n] + Bg[q]*dbu;
      }
    }
  }
  const long base = ((long)(b*NCHUNK + c)*DSTATE)*DINNER + d;
  #pragma unroll
  for (int n=0;n<16;n++) S[base + (long)n*DINNER] = s[n];
  sdelta[(long)(b*NCHUNK+c)*DINNER + d] = sd;
}

// K2: prefix across chunks per (b,d,n). Writes Xin (state entering chunk c)
// and last_state output. P_c = exp(a * sum_delta_c).
__global__ __launch_bounds__(256) void scan_part2(
    const float* __restrict__ S,
    const float* __restrict__ sdelta,
    const float* __restrict__ Amat,
    float* __restrict__ Xin,
    float* __restrict__ last_state)
{
  int id = blockIdx.x*256 + threadIdx.x;   // ((b*16+n)*4096 + d)
  int d = id & (DINNER-1);
  int n = (id>>12) & 15;
  int b = id>>16;
  float a = Amat[n*DINNER+d];
  float X = 0.f;
  #pragma unroll
  for (int c=0;c<NCHUNK;c++){
    long sb = ((long)(b*NCHUNK+c)*DSTATE + n)*DINNER + d;
    Xin[sb] = X;
    float sd = sdelta[(long)(b*NCHUNK+c)*DINNER + d];
    float Sc = S[sb];
    X = __expf(a*sd)*X + Sc;
  }
  last_state[((long)b*DSTATE + n)*DINNER + d] = X;
}

// K3: re-run each chunk from its true entering state; produce y (bf16, (m,d)).
// y_b may alias u_b: each (m,d) read (delta/u/z) completes before the same
// thread's y store to that (m,d); other threads never touch this (m,d).
__global__ __launch_bounds__(256) void scan_part3(
    const unsigned short* __restrict__ delta_b,
    const unsigned short* __restrict__ u_b,
    const unsigned short* __restrict__ z_b,
    const float* __restrict__ xdbl,
    const float* __restrict__ Amat,
    const float* __restrict__ Dvec,
    const float* __restrict__ Xin,
    unsigned short* __restrict__ y_b)
{
  const int t = threadIdx.x;
  const int blk = blockIdx.x;
  const int c = blk & 15, b = (blk>>4)&3, d = (blk>>6)*256 + t;
  float a[16], s[16];
  const long xb0 = ((long)(b*NCHUNK + c)*DSTATE)*DINNER + d;
  #pragma unroll
  for (int n=0;n<16;n++){
    a[n] = Amat[n*DINNER+d];
    s[n] = Xin[xb0 + (long)n*DINNER];
  }
  const float Dd = Dvec[d];
  const long mbase = (long)b*SEQ + c*LC;
  for (int l=0;l<LC;l++){
    long m = mbase + l;
    float dl = bf2f(delta_b[m*DINNER+d]);
    float ul = bf2f(u_b[m*DINNER+d]);
    float zl = bf2f(z_b[m*DINNER+d]);
    const float* xb = &xdbl[m*160 + 128];
    float dbu = dl*ul;
    float y = 0.f;
    #pragma unroll
    for (int g=0; g<4; g++){
      fvec4 Bg = *(const fvec4*)(xb + 4*g);
      fvec4 Cg = *(const fvec4*)(xb + 16 + 4*g);
      #pragma unroll
      for (int q=0;q<4;q++){
        int n = g*4+q;
        s[n] = __expf(dl*a[n])*s[n] + Bg[q]*dbu;
        y += Cg[q]*s[n];
      }
    }
    float yy = y + ul*Dd;
    float zs = zl*sigf(zl);
    y_b[m*DINNER+d] = f2bf(yy*zs);
  }
}

// ---------------- launcher ----------------
// Aliased 256 MiB layout:
//   Slot A [0,64M):    hs_b(32M)+w_in_b(32M) -> delta(64M) after in_proj
//   Slot B [64,128M):  x(64M) -> after conv: wxp@64 wdt@66 wout@68 xdbl@84
//                      dtr@90 S@92(16M) Xin@108(16M) sdelta@124(1M)
//   Slot C [128,192M): z(64M)
//   Slot D [192,256M): u(64M) -> y written in-place by scan_part3
extern "C" void kernel_launch(void* const* d_in, const int* in_sizes, int n_in,
                              void* d_out, int out_size, void* d_ws, size_t ws_size,
                              hipStream_t stream) {
  const float* hs     = (const float*)d_in[0];
  const float* w_in   = (const float*)d_in[6];
  const float* conv_w = (const float*)d_in[7];
  const float* conv_b = (const float*)d_in[8];
  const float* w_xp   = (const float*)d_in[9];
  const float* w_dt   = (const float*)d_in[10];
  const float* dt_bias= (const float*)d_in[11];
  const float* Amat   = (const float*)d_in[12];
  const float* Dvec   = (const float*)d_in[13];
  const float* w_out  = (const float*)d_in[14];
  float* out = (float*)d_out;

  char* ws = (char*)d_ws;
  const size_t MiB = (size_t)1 << 20;

  unsigned short *hs_b, *w_in_b, *x_b, *z_b, *u_b, *delta_b;
  unsigned short *wxp_b, *wdt_b, *wout_b, *dtr_b, *y_b;
  float *xdbl, *Sbuf, *Xin, *sdelta;

  if (ws_size >= 400*MiB){
    size_t off = 0;
    auto alloc = [&](size_t bytes)->void*{ void* p = ws + off; off += (bytes + 255) & ~(size_t)255; return p; };
    hs_b   = (unsigned short*)alloc((size_t)MROWS*DMODEL*2);
    w_in_b = (unsigned short*)alloc((size_t)2*DINNER*DMODEL*2);
    x_b    = (unsigned short*)alloc((size_t)MROWS*DINNER*2);
    z_b    = (unsigned short*)alloc((size_t)MROWS*DINNER*2);
    u_b    = (unsigned short*)alloc((size_t)MROWS*DINNER*2);
    delta_b= (unsigned short*)alloc((size_t)MROWS*DINNER*2);
    wxp_b  = (unsigned short*)alloc((size_t)160*DINNER*2);
    wdt_b  = (unsigned short*)alloc((size_t)DINNER*DTRANK*2);
    wout_b = (unsigned short*)alloc((size_t)DMODEL*DINNER*2);
    xdbl   = (float*)alloc((size_t)MROWS*160*4);
    dtr_b  = (unsigned short*)alloc((size_t)MROWS*DTRANK*2);
    Sbuf   = (float*)alloc((size_t)NB*NCHUNK*DSTATE*DINNER*4);
    Xin    = (float*)alloc((size_t)NB*NCHUNK*DSTATE*DINNER*4);
    sdelta = (float*)alloc((size_t)NB*NCHUNK*DINNER*4);
    y_b    = x_b;
  } else {
    hs_b    = (unsigned short*)(ws + 0);
    w_in_b  = (unsigned short*)(ws + 32*MiB);
    delta_b = (unsigned short*)(ws + 0);
    x_b     = (unsigned short*)(ws + 64*MiB);
    wxp_b   = (unsigned short*)(ws + 64*MiB);
    wdt_b   = (unsigned short*)(ws + 66*MiB);
    wout_b  = (unsigned short*)(ws + 68*MiB);
    xdbl    = (float*)         (ws + 84*MiB);
    dtr_b   = (unsigned short*)(ws + 90*MiB);
    Sbuf    = (float*)         (ws + 92*MiB);
    Xin     = (float*)         (ws + 108*MiB);
    sdelta  = (float*)         (ws + 124*MiB);
    z_b     = (unsigned short*)(ws + 128*MiB);
    u_b     = (unsigned short*)(ws + 192*MiB);
    y_b     = u_b;   // in-place (see scan_part3 note)
  }

  // 1) converts needed for in_proj
  cvt_bf16_kernel<<<(MROWS*DMODEL)/1024, 256, 0, stream>>>(hs, hs_b, MROWS*DMODEL);
  cvt_bf16_kernel<<<(2*DINNER*DMODEL)/1024, 256, 0, stream>>>(w_in, w_in_b, 2*DINNER*DMODEL);

  // 2) in_proj
  gemm_bt<0><<<dim3(64,64), 256, 0, stream>>>(hs_b, w_in_b, DMODEL, 2*DINNER,
                                              nullptr, x_b, z_b, nullptr, 0);
  // 3) new_conv_state
  conv_state_kernel<<<256, 256, 0, stream>>>(x_b, out + (size_t)MROWS*DMODEL);
  // 4) conv + silu -> u (x dead afterwards)
  conv_silu_kernel<<<(MROWS*512)/256, 256, 0, stream>>>(x_b, conv_w, conv_b, u_b);

  // 5) weight converts (into dead-x slot in aliased mode)
  cvt_bf16_kernel<<<(160*DINNER)/1024, 256, 0, stream>>>(w_xp, wxp_b, 160*DINNER);
  cvt_bf16_kernel<<<(DINNER*DTRANK)/1024, 256, 0, stream>>>(w_dt, wdt_b, DINNER*DTRANK);
  cvt_bf16_kernel<<<(DMODEL*DINNER)/1024, 256, 0, stream>>>(w_out, wout_b, DMODEL*DINNER);

  // 6) x_proj -> xdbl fp32
  gemm_bt<1><<<dim3(2,64), 256, 0, stream>>>(u_b, wxp_b, DINNER, 160,
                                             xdbl, nullptr, nullptr, nullptr, 160);
  // 7) dtr bf16
  cvt_dtr_kernel<<<(MROWS*32)/256, 256, 0, stream>>>(xdbl, dtr_b);
  // 8) dt_proj + softplus -> delta
  gemm_bt<2><<<dim3(32,64), 256, 0, stream>>>(dtr_b, wdt_b, DTRANK, DINNER,
                                              nullptr, delta_b, nullptr, dt_bias, DINNER);
  // 9) chunked scan
  scan_part1<<<1024, 256, 0, stream>>>(delta_b, u_b, xdbl, Amat, Sbuf, sdelta);
  scan_part2<<<1024, 256, 0, stream>>>(Sbuf, sdelta, Amat, Xin,
                                       out + (size_t)MROWS*DMODEL + NB*DINNER*4);
  scan_part3<<<1024, 256, 0, stream>>>(delta_b, u_b, z_b, xdbl, Amat, Dvec, Xin, y_b);
  // 10) out_proj
  gemm_bt<3><<<dim3(16,64), 256, 0, stream>>>(y_b, wout_b, DINNER, DMODEL,
                                              out, nullptr, nullptr, nullptr, DMODEL);
}

// Round 4
// 1016.408 us; speedup vs baseline: 1.6930x; 1.1449x over previous
//
#include <hip/hip_runtime.h>
#include <hip/hip_bf16.h>
#include <math.h>

typedef __attribute__((ext_vector_type(4))) float fvec4;
typedef __attribute__((ext_vector_type(2))) float fvec2;
typedef __attribute__((ext_vector_type(4))) int ivec4;
typedef __attribute__((ext_vector_type(4))) unsigned short usvec4;
typedef __attribute__((ext_vector_type(8))) short bf16x8;

#define SEQ 2048
#define DMODEL 2048
#define DINNER 4096
#define DSTATE 16
#define DTRANK 128
#define NB 4
#define MROWS (NB*SEQ)  // 8192
#define NCHUNK 16
#define LC (SEQ/NCHUNK) // 128

__device__ __forceinline__ float bf2f(unsigned short h){
  union{unsigned int u; float f;} v; v.u = ((unsigned int)h)<<16; return v.f;
}
__device__ __forceinline__ unsigned short f2bf(float f){
  union{float f; unsigned int u;} v; v.f=f;
  unsigned int r = v.u + 0x7fffu + ((v.u>>16)&1u);
  return (unsigned short)(r>>16);
}
__device__ __forceinline__ void async16(const void* g, void* l){
  __builtin_amdgcn_global_load_lds((const __attribute__((address_space(1))) void*)g,
                                   (__attribute__((address_space(3))) void*)l, 16, 0, 0);
}
__device__ __forceinline__ float sigf(float x){ return 1.f/(1.f+__expf(-x)); }

// ---------------- fp32 -> bf16 convert ----------------
__global__ void cvt_bf16_kernel(const float* __restrict__ in, unsigned short* __restrict__ out, int n){
  int i = (blockIdx.x*256 + threadIdx.x)*4;
  if (i >= n) return;
  fvec4 v = *(const fvec4*)(in + i);
  usvec4 o;
  o[0]=f2bf(v[0]); o[1]=f2bf(v[1]); o[2]=f2bf(v[2]); o[3]=f2bf(v[3]);
  *(usvec4*)(out + i) = o;
}

// ================= 256x256 ring-pipelined GEMM (C = A * B^T) =================
// BK=32, 4-slot LDS ring (128 KiB), counted vmcnt(12) => 3 K-tiles of slack,
// raw s_barrier (no vmcnt0 drain), T2 XOR-swizzle (global-source + ds_read),
// T1 XCD-aware block swizzle. 512 threads = 8 waves (2M x 4N), wave tile 128x64.
// MODE 0: split x/z bf16 at col 4096 (in_proj). MODE 3: fp32 store (out_proj).
template<int MODE>
__global__ __launch_bounds__(512, 2) void gemm256(
    const unsigned short* __restrict__ A,
    const unsigned short* __restrict__ B,
    int K, int nbx, int ldc,
    unsigned short* __restrict__ Cb1,
    unsigned short* __restrict__ Cb2,
    float* __restrict__ Cf)
{
  __shared__ __align__(16) unsigned short lds[65536];  // 4 slots x 32 KiB
  char* ldsc = (char*)lds;
  const int t = threadIdx.x;

  // T1: XCD swizzle (gridDim.x % 8 == 0 for all uses)
  const int nwg = gridDim.x;
  const int cpx = nwg >> 3;
  const int bid = blockIdx.x;
  const int swzb = (bid & 7)*cpx + (bid >> 3);
  const int bx = swzb % nbx, by = swzb / nbx;

  // staging source precompute (swizzle involution on the 16 KiB operand region)
  const int bA0 = t*16, bA1 = 8192 + t*16;
  const int sw0 = bA0 ^ (((bA0>>6)&3)<<4);
  const int sw1 = bA1 ^ (((bA1>>6)&3)<<4);
  const int gr0 = sw0>>6, gc0 = (sw0&63)>>1;
  const int gr1 = sw1>>6, gc1 = (sw1&63)>>1;
  const unsigned short* Ab = A + (long)by*256*K;
  const unsigned short* Bb = B + (long)bx*256*K;
  const unsigned short* gA0 = Ab + (long)gr0*K + gc0;
  const unsigned short* gA1 = Ab + (long)gr1*K + gc1;
  const unsigned short* gB0 = Bb + (long)gr0*K + gc0;
  const unsigned short* gB1 = Bb + (long)gr1*K + gc1;

  // fragment read offsets (swizzled)
  const int wid = t>>6, lane = t&63;
  const int wm = wid>>2, wn = wid&3;
  const int fr = lane&15, fc = lane>>4;
  const int cb = (fc<<4) ^ ((fr&3)<<4);
  const int offA = (wm*128 + fr)*64 + cb;            // + i*1024
  const int offB = 16384 + (wn*64 + fr)*64 + cb;     // + j*1024

  fvec4 acc[8][4];
  #pragma unroll
  for (int i=0;i<8;i++){
    #pragma unroll
    for (int j=0;j<4;j++) acc[i][j] = (fvec4)(0.f);
  }

  const int NKT = K >> 5;
  auto stage = [&](int slot, int k0){
    char* sb = ldsc + slot*32768;
    async16(gA0 + k0, sb + t*16);
    async16(gA1 + k0, sb + 8192 + t*16);
    async16(gB0 + k0, sb + 16384 + t*16);
    async16(gB1 + k0, sb + 24576 + t*16);
  };

  // prologue: 3 K-tiles in flight
  stage(0, 0); stage(1, 32); stage(2, 64);

  for (int kt = 0; kt < NKT; ++kt){
    int ks = kt + 3; if (ks > NKT-1) ks = NKT-1;     // tail: re-fetch last tile into dead slot
    stage((kt+3)&3, ks*32);
    asm volatile("s_waitcnt vmcnt(12)" ::: "memory"); // kt's 4 loads (oldest) complete
    __builtin_amdgcn_s_barrier();                     // all waves' kt loads complete
    const char* sb = ldsc + (kt&3)*32768;
    bf16x8 af[8], bv[4];
    #pragma unroll
    for (int i=0;i<8;i++) af[i] = *(const bf16x8*)(sb + offA + i*1024);
    #pragma unroll
    for (int j=0;j<4;j++) bv[j] = *(const bf16x8*)(sb + offB + j*1024);
    __builtin_amdgcn_s_setprio(1);
    #pragma unroll
    for (int i=0;i<8;i++){
      #pragma unroll
      for (int j=0;j<4;j++){
        acc[i][j] = __builtin_amdgcn_mfma_f32_16x16x32_bf16(af[i], bv[j], acc[i][j], 0,0,0);
      }
    }
    __builtin_amdgcn_s_setprio(0);
    __builtin_amdgcn_s_barrier();                     // slot (kt&3) free for reuse
  }

  const long crow0 = (long)by*256 + wm*128;
  const int  ccol0 = bx*256 + wn*64;
  #pragma unroll
  for (int i=0;i<8;i++){
    #pragma unroll
    for (int j=0;j<4;j++){
      #pragma unroll
      for (int q=0;q<4;q++){
        long rg = crow0 + i*16 + fc*4 + q;
        int  cg = ccol0 + j*16 + fr;
        float v = acc[i][j][q];
        if (MODE==0){
          if (cg < DINNER) Cb1[rg*DINNER + cg] = f2bf(v);
          else             Cb2[rg*DINNER + (cg-DINNER)] = f2bf(v);
        } else {
          Cf[rg*(long)ldc + cg] = v;
        }
      }
    }
  }
}

// ---------------- m97-style 128x128 GEMM for the small projections ----------------
// MODE 1: fp32 store, guard col<Nreal (x_proj)
// MODE 2: softplus(v+bias) -> bf16 (dt_proj -> delta)
template<int MODE>
__global__ __launch_bounds__(256) void gemm_bt(
    const unsigned short* __restrict__ A,
    const unsigned short* __restrict__ B,
    int K, int Nreal,
    float* __restrict__ Cf,
    unsigned short* __restrict__ Cb1,
    const float* __restrict__ bias,
    int ldc)
{
  __shared__ __align__(16) unsigned short As[128*32];
  __shared__ __align__(16) unsigned short Bs[128*32];
  const int t = threadIdx.x;
  const int bx = blockIdx.x, by = blockIdx.y;
  const int wave = t>>6, lane = t&63;
  const int wr = (wave>>1)*64, wc = (wave&1)*64;
  const int fr = lane&15, fc = lane>>4;
  fvec4 acc[4][4];
  #pragma unroll
  for(int i=0;i<4;i++){
    #pragma unroll
    for(int j=0;j<4;j++){ acc[i][j] = (fvec4)(0.f); }
  }
  const int srow = t>>2;
  const int scol = (t&3)*8;
  long rowA = (long)by*128 + srow;
  int rB0 = bx*128 + srow;      if (rB0 > Nreal-1) rB0 = Nreal-1;
  int rB1 = bx*128 + 64 + srow; if (rB1 > Nreal-1) rB1 = Nreal-1;
  const unsigned short* gA0 = A + rowA*(long)K + scol;
  const unsigned short* gA1 = gA0 + 64L*K;
  const unsigned short* gB0 = B + (long)rB0*K + scol;
  const unsigned short* gB1 = B + (long)rB1*K + scol;
  unsigned short* lA0 = &As[t*8];
  unsigned short* lA1 = &As[2048 + t*8];
  unsigned short* lB0 = &Bs[t*8];
  unsigned short* lB1 = &Bs[2048 + t*8];

  for (int k0 = 0; k0 < K; k0 += 32){
    async16(gA0 + k0, lA0);
    async16(gA1 + k0, lA1);
    async16(gB0 + k0, lB0);
    async16(gB1 + k0, lB1);
    __syncthreads();
    bf16x8 af[4], bv[4];
    #pragma unroll
    for(int i=0;i<4;i++){
      af[i] = *(const bf16x8*)&As[(wr + i*16 + fr)*32 + fc*8];
      bv[i] = *(const bf16x8*)&Bs[(wc + i*16 + fr)*32 + fc*8];
    }
    #pragma unroll
    for(int i=0;i<4;i++){
      #pragma unroll
      for(int j=0;j<4;j++){
        acc[i][j] = __builtin_amdgcn_mfma_f32_16x16x32_bf16(af[i], bv[j], acc[i][j], 0,0,0);
      }
    }
    __syncthreads();
  }

  const long crow0 = (long)by*128 + wr;
  const int ccol0 = bx*128 + wc;
  #pragma unroll
  for(int i=0;i<4;i++){
    #pragma unroll
    for(int j=0;j<4;j++){
      #pragma unroll
      for(int q=0;q<4;q++){
        long rg = crow0 + i*16 + fc*4 + q;
        int  cg = ccol0 + j*16 + fr;
        float v = acc[i][j][q];
        if (MODE==1){
          if (cg < Nreal) Cf[rg*ldc + cg] = v;
        } else if (MODE==2){
          float x = v + bias[cg];
          float sp = (x > 20.f) ? x : log1pf(__expf(x));
          Cb1[rg*ldc + cg] = f2bf(sp);
        }
      }
    }
  }
}

// ---------------- depthwise causal conv(4) + bias + SiLU ----------------
__global__ __launch_bounds__(256) void conv_silu_kernel(
    const unsigned short* __restrict__ xb, const float* __restrict__ w,
    const float* __restrict__ bias, unsigned short* __restrict__ ub)
{
  int gid = blockIdx.x*256 + threadIdx.x;
  int d0 = (gid & 511)*8;
  long m = gid >> 9;
  int l = (int)(m & (SEQ-1));
  fvec4 w4[8];
  #pragma unroll
  for(int k=0;k<8;k++) w4[k] = *(const fvec4*)&w[(d0+k)*4];
  float acc[8];
  fvec4 b0 = *(const fvec4*)&bias[d0];
  fvec4 b1 = *(const fvec4*)&bias[d0+4];
  acc[0]=b0[0];acc[1]=b0[1];acc[2]=b0[2];acc[3]=b0[3];
  acc[4]=b1[0];acc[5]=b1[1];acc[6]=b1[2];acc[7]=b1[3];
  #pragma unroll
  for(int j=0;j<4;j++){
    int lj = l-3+j;
    if (lj >= 0){
      ivec4 xv = *(const ivec4*)&xb[(m-3+j)*DINNER + d0];
      float xs[8];
      #pragma unroll
      for(int q=0;q<4;q++){
        unsigned int wd = (unsigned int)xv[q];
        xs[2*q]   = bf2f((unsigned short)(wd & 0xffffu));
        xs[2*q+1] = bf2f((unsigned short)(wd >> 16));
      }
      #pragma unroll
      for(int k=0;k<8;k++) acc[k] += xs[k]*w4[k][j];
    }
  }
  ivec4 ov;
  #pragma unroll
  for(int q=0;q<4;q++){
    float y0 = acc[2*q]  * sigf(acc[2*q]);
    float y1 = acc[2*q+1]* sigf(acc[2*q+1]);
    ov[q] = (int)((unsigned)f2bf(y0) | ((unsigned)f2bf(y1) << 16));
  }
  *(ivec4*)&ub[m*DINNER + d0] = ov;
}

// ---------------- new_conv_state ----------------
__global__ void conv_state_kernel(const unsigned short* __restrict__ xb, float* __restrict__ out){
  int i = blockIdx.x*256 + threadIdx.x;
  int b = i >> 14; int r = i & 16383; int dd = r >> 2; int j = r & 3;
  out[i] = bf2f(xb[((long)(b*SEQ + (SEQ-4) + j))*DINNER + dd]);
}

// ---------------- xdbl[:, :128] -> bf16 for dt_proj A ----------------
__global__ void cvt_dtr_kernel(const float* __restrict__ xdbl, unsigned short* __restrict__ dtr){
  int i = blockIdx.x*256 + threadIdx.x;
  long mrow = i >> 5; int c = (i & 31)*4;
  fvec4 v = *(const fvec4*)&xdbl[mrow*160 + c];
  usvec4 o; o[0]=f2bf(v[0]); o[1]=f2bf(v[1]); o[2]=f2bf(v[2]); o[3]=f2bf(v[3]);
  *(usvec4*)&dtr[mrow*DTRANK + c] = o;
}

// ================= chunked parallel scan =================
__global__ __launch_bounds__(256) void scan_part1(
    const unsigned short* __restrict__ delta_b,
    const unsigned short* __restrict__ u_b,
    const float* __restrict__ xdbl,
    const float* __restrict__ Amat,
    float* __restrict__ S,
    float* __restrict__ sdelta)
{
  const int t = threadIdx.x;
  const int blk = blockIdx.x;
  const int c = blk & 15, b = (blk>>4)&3, d = (blk>>6)*256 + t;
  float a[16], s[16];
  #pragma unroll
  for (int n=0;n<16;n++){ a[n] = Amat[n*DINNER+d]; s[n]=0.f; }
  float sd = 0.f;
  const long mbase = (long)b*SEQ + c*LC;
  for (int l=0;l<LC;l++){
    long m = mbase + l;
    float dl = bf2f(delta_b[m*DINNER+d]);
    float ul = bf2f(u_b[m*DINNER+d]);
    const float* xb = &xdbl[m*160 + 128];
    float dbu = dl*ul;
    sd += dl;
    #pragma unroll
    for (int g=0; g<4; g++){
      fvec4 Bg = *(const fvec4*)(xb + 4*g);
      #pragma unroll
      for (int q=0;q<4;q++){
        int n = g*4+q;
        s[n] = __expf(dl*a[n])*s[n] + Bg[q]*dbu;
      }
    }
  }
  const long base = ((long)(b*NCHUNK + c)*DSTATE)*DINNER + d;
  #pragma unroll
  for (int n=0;n<16;n++) S[base + (long)n*DINNER] = s[n];
  sdelta[(long)(b*NCHUNK+c)*DINNER + d] = sd;
}

__global__ __launch_bounds__(256) void scan_part2(
    const float* __restrict__ S,
    const float* __restrict__ sdelta,
    const float* __restrict__ Amat,
    float* __restrict__ Xin,
    float* __restrict__ last_state)
{
  int id = blockIdx.x*256 + threadIdx.x;
  int d = id & (DINNER-1);
  int n = (id>>12) & 15;
  int b = id>>16;
  float a = Amat[n*DINNER+d];
  float X = 0.f;
  #pragma unroll
  for (int c=0;c<NCHUNK;c++){
    long sb = ((long)(b*NCHUNK+c)*DSTATE + n)*DINNER + d;
    Xin[sb] = X;
    float sd = sdelta[(long)(b*NCHUNK+c)*DINNER + d];
    float Sc = S[sb];
    X = __expf(a*sd)*X + Sc;
  }
  last_state[((long)b*DSTATE + n)*DINNER + d] = X;
}

__global__ __launch_bounds__(256) void scan_part3(
    const unsigned short* __restrict__ delta_b,
    const unsigned short* __restrict__ u_b,
    const unsigned short* __restrict__ z_b,
    const float* __restrict__ xdbl,
    const float* __restrict__ Amat,
    const float* __restrict__ Dvec,
    const float* __restrict__ Xin,
    unsigned short* __restrict__ y_b)
{
  const int t = threadIdx.x;
  const int blk = blockIdx.x;
  const int c = blk & 15, b = (blk>>4)&3, d = (blk>>6)*256 + t;
  float a[16], s[16];
  const long xb0 = ((long)(b*NCHUNK + c)*DSTATE)*DINNER + d;
  #pragma unroll
  for (int n=0;n<16;n++){
    a[n] = Amat[n*DINNER+d];
    s[n] = Xin[xb0 + (long)n*DINNER];
  }
  const float Dd = Dvec[d];
  const long mbase = (long)b*SEQ + c*LC;
  for (int l=0;l<LC;l++){
    long m = mbase + l;
    float dl = bf2f(delta_b[m*DINNER+d]);
    float ul = bf2f(u_b[m*DINNER+d]);
    float zl = bf2f(z_b[m*DINNER+d]);
    const float* xb = &xdbl[m*160 + 128];
    float dbu = dl*ul;
    float y = 0.f;
    #pragma unroll
    for (int g=0; g<4; g++){
      fvec4 Bg = *(const fvec4*)(xb + 4*g);
      fvec4 Cg = *(const fvec4*)(xb + 16 + 4*g);
      #pragma unroll
      for (int q=0;q<4;q++){
        int n = g*4+q;
        s[n] = __expf(dl*a[n])*s[n] + Bg[q]*dbu;
        y += Cg[q]*s[n];
      }
    }
    float yy = y + ul*Dd;
    float zs = zl*sigf(zl);
    y_b[m*DINNER+d] = f2bf(yy*zs);
  }
}

// ---------------- launcher ----------------
// Aliased 256 MiB layout:
//   Slot A [0,64M):    hs_b(32M)+w_in_b(32M) -> delta(64M) after in_proj
//   Slot B [64,128M):  x(64M) -> after conv: wxp@64 wdt@66 wout@68 xdbl@84
//                      dtr@90 S@92(16M) Xin@108(16M) sdelta@124(1M)
//   Slot C [128,192M): z(64M)
//   Slot D [192,256M): u(64M) -> y written in-place by scan_part3
extern "C" void kernel_launch(void* const* d_in, const int* in_sizes, int n_in,
                              void* d_out, int out_size, void* d_ws, size_t ws_size,
                              hipStream_t stream) {
  const float* hs     = (const float*)d_in[0];
  const float* w_in   = (const float*)d_in[6];
  const float* conv_w = (const float*)d_in[7];
  const float* conv_b = (const float*)d_in[8];
  const float* w_xp   = (const float*)d_in[9];
  const float* w_dt   = (const float*)d_in[10];
  const float* dt_bias= (const float*)d_in[11];
  const float* Amat   = (const float*)d_in[12];
  const float* Dvec   = (const float*)d_in[13];
  const float* w_out  = (const float*)d_in[14];
  float* out = (float*)d_out;

  char* ws = (char*)d_ws;
  const size_t MiB = (size_t)1 << 20;

  unsigned short *hs_b, *w_in_b, *x_b, *z_b, *u_b, *delta_b;
  unsigned short *wxp_b, *wdt_b, *wout_b, *dtr_b, *y_b;
  float *xdbl, *Sbuf, *Xin, *sdelta;

  if (ws_size >= 400*MiB){
    size_t off = 0;
    auto alloc = [&](size_t bytes)->void*{ void* p = ws + off; off += (bytes + 255) & ~(size_t)255; return p; };
    hs_b   = (unsigned short*)alloc((size_t)MROWS*DMODEL*2);
    w_in_b = (unsigned short*)alloc((size_t)2*DINNER*DMODEL*2);
    x_b    = (unsigned short*)alloc((size_t)MROWS*DINNER*2);
    z_b    = (unsigned short*)alloc((size_t)MROWS*DINNER*2);
    u_b    = (unsigned short*)alloc((size_t)MROWS*DINNER*2);
    delta_b= (unsigned short*)alloc((size_t)MROWS*DINNER*2);
    wxp_b  = (unsigned short*)alloc((size_t)160*DINNER*2);
    wdt_b  = (unsigned short*)alloc((size_t)DINNER*DTRANK*2);
    wout_b = (unsigned short*)alloc((size_t)DMODEL*DINNER*2);
    xdbl   = (float*)alloc((size_t)MROWS*160*4);
    dtr_b  = (unsigned short*)alloc((size_t)MROWS*DTRANK*2);
    Sbuf   = (float*)alloc((size_t)NB*NCHUNK*DSTATE*DINNER*4);
    Xin    = (float*)alloc((size_t)NB*NCHUNK*DSTATE*DINNER*4);
    sdelta = (float*)alloc((size_t)NB*NCHUNK*DINNER*4);
    y_b    = x_b;
  } else {
    hs_b    = (unsigned short*)(ws + 0);
    w_in_b  = (unsigned short*)(ws + 32*MiB);
    delta_b = (unsigned short*)(ws + 0);
    x_b     = (unsigned short*)(ws + 64*MiB);
    wxp_b   = (unsigned short*)(ws + 64*MiB);
    wdt_b   = (unsigned short*)(ws + 66*MiB);
    wout_b  = (unsigned short*)(ws + 68*MiB);
    xdbl    = (float*)         (ws + 84*MiB);
    dtr_b   = (unsigned short*)(ws + 90*MiB);
    Sbuf    = (float*)         (ws + 92*MiB);
    Xin     = (float*)         (ws + 108*MiB);
    sdelta  = (float*)         (ws + 124*MiB);
    z_b     = (unsigned short*)(ws + 128*MiB);
    u_b     = (unsigned short*)(ws + 192*MiB);
    y_b     = u_b;
  }

  // 1) converts needed for in_proj
  cvt_bf16_kernel<<<(MROWS*DMODEL)/1024, 256, 0, stream>>>(hs, hs_b, MROWS*DMODEL);
  cvt_bf16_kernel<<<(2*DINNER*DMODEL)/1024, 256, 0, stream>>>(w_in, w_in_b, 2*DINNER*DMODEL);

  // 2) in_proj: (8192x2048)@(8192x2048)^T, 256^2 tiles -> 32x32=1024 blocks
  gemm256<0><<<1024, 512, 0, stream>>>(hs_b, w_in_b, DMODEL, 32, 0,
                                       x_b, z_b, nullptr);
  // 3) new_conv_state
  conv_state_kernel<<<256, 256, 0, stream>>>(x_b, out + (size_t)MROWS*DMODEL);
  // 4) conv + silu -> u (x dead afterwards)
  conv_silu_kernel<<<(MROWS*512)/256, 256, 0, stream>>>(x_b, conv_w, conv_b, u_b);

  // 5) weight converts (into dead-x slot in aliased mode)
  cvt_bf16_kernel<<<(160*DINNER)/1024, 256, 0, stream>>>(w_xp, wxp_b, 160*DINNER);
  cvt_bf16_kernel<<<(DINNER*DTRANK)/1024, 256, 0, stream>>>(w_dt, wdt_b, DINNER*DTRANK);
  cvt_bf16_kernel<<<(DMODEL*DINNER)/1024, 256, 0, stream>>>(w_out, wout_b, DMODEL*DINNER);

  // 6) x_proj -> xdbl fp32
  gemm_bt<1><<<dim3(2,64), 256, 0, stream>>>(u_b, wxp_b, DINNER, 160,
                                             xdbl, nullptr, nullptr, 160);
  // 7) dtr bf16
  cvt_dtr_kernel<<<(MROWS*32)/256, 256, 0, stream>>>(xdbl, dtr_b);
  // 8) dt_proj + softplus -> delta
  gemm_bt<2><<<dim3(32,64), 256, 0, stream>>>(dtr_b, wdt_b, DTRANK, DINNER,
                                              nullptr, delta_b, dt_bias, DINNER);
  // 9) chunked scan
  scan_part1<<<1024, 256, 0, stream>>>(delta_b, u_b, xdbl, Amat, Sbuf, sdelta);
  scan_part2<<<1024, 256, 0, stream>>>(Sbuf, sdelta, Amat, Xin,
                                       out + (size_t)MROWS*DMODEL + NB*DINNER*4);
  scan_part3<<<1024, 256, 0, stream>>>(delta_b, u_b, z_b, xdbl, Amat, Dvec, Xin, y_b);
  // 10) out_proj: (8192x4096)@(2048x4096)^T, 32x8=256 blocks
  gemm256<3><<<256, 512, 0, stream>>>(y_b, wout_b, DINNER, 8, DMODEL,
                                      nullptr, nullptr, out);
}